// Round 11
// baseline (47.210 us; speedup 1.0000x reference)
//
#include <hip/hip_runtime.h>

#define EPSV 1e-5f

typedef __fp16 f16x8 __attribute__((ext_vector_type(8)));
typedef float f32x4 __attribute__((ext_vector_type(4)));
typedef __fp16 half2v __attribute__((ext_vector_type(2)));

__device__ __forceinline__ unsigned h2_as_u32(half2v h) {
    union { half2v h; unsigned u; } cv;
    cv.h = h;
    return cv.u;
}

#define LROWS 76
#define LSTRIDE 88  // halves; 176B rows, 16B-aligned; 11-chunk stride (odd) -> benign

// ---------------------------------------------------------------------------
// Kernel 1: fold the 3 branches into one 13x13 kernel + bias; emit per-channel
// MFMA B-fragments: for each dy, 32x16 banded Toeplitz B_dy[k][i] = w[dy][k-i-2]
// in v_mfma_f32_16x16x32_f16 B-fragment order (lane l: i=l&15, k=8*(l>>4)+j).
// ---------------------------------------------------------------------------
__global__ __launch_bounds__(256) void fuse_weights(
    const float* __restrict__ w_large, const float* __restrict__ w_small,
    const float* __restrict__ g_l, const float* __restrict__ b_l,
    const float* __restrict__ m_l, const float* __restrict__ v_l,
    const float* __restrict__ g_s, const float* __restrict__ b_s,
    const float* __restrict__ m_s, const float* __restrict__ v_s,
    const float* __restrict__ g_i, const float* __restrict__ b_i,
    const float* __restrict__ m_i, const float* __restrict__ v_i,
    float* __restrict__ bf, uint4* __restrict__ wB) {
    __shared__ float sw[169];
    const int c = blockIdx.x;
    const int t = threadIdx.x;
    const float sl = g_l[c] * rsqrtf(v_l[c] + EPSV);
    const float ss = g_s[c] * rsqrtf(v_s[c] + EPSV);
    const float si = g_i[c] * rsqrtf(v_i[c] + EPSV);
    if (t < 169) {
        const int ky = t / 13, kx = t % 13;
        float w = w_large[c * 169 + t] * sl;
        if (ky >= 5 && ky <= 7 && kx >= 5 && kx <= 7)
            w += w_small[c * 9 + (ky - 5) * 3 + (kx - 5)] * ss;
        if (t == 6 * 13 + 6) w += si;
        sw[t] = w;
    }
    if (t == 0)
        bf[c] = (b_l[c] - m_l[c] * sl) + (b_s[c] - m_s[c] * ss) +
                (b_i[c] - m_i[c] * si);
    __syncthreads();
    for (int it = t; it < 832; it += 256) {   // 13 dy * 64 lanes
        const int dy = it >> 6;
        const int l = it & 63;
        const int i = l & 15;
        const int kb = (l >> 4) * 8;
        unsigned u[4];
#pragma unroll
        for (int jj = 0; jj < 4; ++jj) {
            const int kx0 = kb + 2 * jj - i - 2;
            const int kx1 = kx0 + 1;
            const float w0 =
                (kx0 >= 0 && kx0 <= 12) ? sw[dy * 13 + kx0] : 0.0f;
            const float w1 =
                (kx1 >= 0 && kx1 <= 12) ? sw[dy * 13 + kx1] : 0.0f;
            u[jj] = h2_as_u32(__builtin_amdgcn_cvt_pkrtz(w0, w1));
        }
        wB[(size_t)c * 832 + it] = make_uint4(u[0], u[1], u[2], u[3]);
    }
}

// ---------------------------------------------------------------------------
// Kernel 2: depthwise 13x13 + bias on matrix cores. One block (4 waves) per
// (n,c) image; zero-padded f16 image in LDS. Wave wv owns 16-col tile
// c0=16*wv and keeps FOUR 16-row accumulators live. dy-OUTER loop: one
// B-fragment in flight (double-buffered from global/L1), 4 ds_read_b128 +
// 4 MFMA per dy -> ~60 regs/wave -> high occupancy. Halo-only zeroing,
// single barrier.
// ---------------------------------------------------------------------------
__global__ __launch_bounds__(256, 6) void dwconv_mfma(
    const float* __restrict__ x, const uint4* __restrict__ wB,
    const float* __restrict__ bf, float* __restrict__ out) {
    __shared__ __align__(16) __fp16 tile[LROWS * LSTRIDE];
    unsigned* tz = (unsigned*)tile;          // u32 view, row stride 44

    const int t = threadIdx.x;
    const int img = blockIdx.x;              // n*384 + c
    const int c = __builtin_amdgcn_readfirstlane(img % 384);
    const size_t base = (size_t)img * 4096;

    // ---- zero halo only (disjoint from interior writes; no barrier between)
    // top rows 0..5 and bottom rows 70..75: u32 0..39 per row, as uint4
    if (t < 120) {
        const int r = t / 10;
        const int rr = (r < 6) ? r : r + 64;
        const int qq = t - r * 10;
        *(uint4*)(tz + rr * 44 + qq * 4) = make_uint4(0u, 0u, 0u, 0u);
    }
    // side strips rows 6..69: u32 {0..3} and {36..39}
    if (t < 128) {
        const int r = 6 + (t >> 1);
        const int sb = (t & 1) ? 36 : 0;
        *(uint4*)(tz + r * 44 + sb) = make_uint4(0u, 0u, 0u, 0u);
    }

    // ---- stage interior: row r = t>>2, 16 f32 at col (t&3)*16 -> f16 ----
    {
        const int r = t >> 2;
        const int q = t & 3;
        const float* src = x + base + r * 64 + q * 16;
        unsigned u[8];
#pragma unroll
        for (int p = 0; p < 4; ++p) {
            const float4 v = ((const float4*)src)[p];
            u[2 * p + 0] = h2_as_u32(__builtin_amdgcn_cvt_pkrtz(v.x, v.y));
            u[2 * p + 1] = h2_as_u32(__builtin_amdgcn_cvt_pkrtz(v.z, v.w));
        }
        unsigned* dst = tz + (r + 6) * 44 + 4 + q * 8;
        *(uint4*)dst = make_uint4(u[0], u[1], u[2], u[3]);
        *(uint4*)(dst + 4) = make_uint4(u[4], u[5], u[6], u[7]);
    }

    const int l = t & 63;
    const int wv = t >> 6;                   // wave id -> c0 = 16*wv
    const int c0 = wv * 16;
    const int lrow = l & 15;
    const int kb = (l >> 4) * 8;
    const __fp16* abase = tile + lrow * LSTRIDE + c0 + kb;
    const uint4* __restrict__ wbp = wB + (size_t)c * 832 + l;
    const float bv = bf[c];

    // first B-fragment load in flight across the barrier
    uint4 bcur = wbp[0];

    f32x4 acc0 = {bv, bv, bv, bv};
    f32x4 acc1 = {bv, bv, bv, bv};
    f32x4 acc2 = {bv, bv, bv, bv};
    f32x4 acc3 = {bv, bv, bv, bv};

    __syncthreads();

#pragma unroll 1
    for (int dy = 0; dy < 13; ++dy) {
        const int dyn = (dy < 12) ? dy + 1 : 12;
        const uint4 bnext = wbp[dyn * 64];
        union { uint4 u; f16x8 h; } bc;
        bc.u = bcur;
        const f16x8 a0 = *(const f16x8*)(abase + (dy) * LSTRIDE);
        const f16x8 a1 = *(const f16x8*)(abase + (16 + dy) * LSTRIDE);
        const f16x8 a2 = *(const f16x8*)(abase + (32 + dy) * LSTRIDE);
        const f16x8 a3 = *(const f16x8*)(abase + (48 + dy) * LSTRIDE);
        acc0 = __builtin_amdgcn_mfma_f32_16x16x32_f16(a0, bc.h, acc0, 0, 0, 0);
        acc1 = __builtin_amdgcn_mfma_f32_16x16x32_f16(a1, bc.h, acc1, 0, 0, 0);
        acc2 = __builtin_amdgcn_mfma_f32_16x16x32_f16(a2, bc.h, acc2, 0, 0, 0);
        acc3 = __builtin_amdgcn_mfma_f32_16x16x32_f16(a3, bc.h, acc3, 0, 0, 0);
        bcur = bnext;
    }

    // C layout: col = c0 + (l&15), rows = 16*rt + 4*(l>>4) + q
    const int ocol = c0 + (l & 15);
    const int orow = 4 * (l >> 4);
    float* ob = out + base;
#pragma unroll
    for (int q = 0; q < 4; ++q) {
        ob[(orow + q) * 64 + ocol] = acc0[q];
        ob[(16 + orow + q) * 64 + ocol] = acc1[q];
        ob[(32 + orow + q) * 64 + ocol] = acc2[q];
        ob[(48 + orow + q) * 64 + ocol] = acc3[q];
    }
}

// ---------------------------------------------------------------------------
extern "C" void kernel_launch(void* const* d_in, const int* in_sizes, int n_in,
                              void* d_out, int out_size, void* d_ws,
                              size_t ws_size, hipStream_t stream) {
    const float* x = (const float*)d_in[0];
    const float* w_large = (const float*)d_in[1];
    const float* w_small = (const float*)d_in[2];
    const float* g_l = (const float*)d_in[3];
    const float* b_l = (const float*)d_in[4];
    const float* m_l = (const float*)d_in[5];
    const float* v_l = (const float*)d_in[6];
    const float* g_s = (const float*)d_in[7];
    const float* b_s = (const float*)d_in[8];
    const float* m_s = (const float*)d_in[9];
    const float* v_s = (const float*)d_in[10];
    const float* g_i = (const float*)d_in[11];
    const float* b_i = (const float*)d_in[12];
    const float* m_i = (const float*)d_in[13];
    const float* v_i = (const float*)d_in[14];
    float* outp = (float*)d_out;

    // ws layout: bf[384] f32 | wB[384*832] uint4 (5.11 MB)
    float* bfp = (float*)d_ws;
    uint4* wB = (uint4*)(bfp + 384);

    fuse_weights<<<384, 256, 0, stream>>>(w_large, w_small, g_l, b_l, m_l, v_l,
                                          g_s, b_s, m_s, v_s, g_i, b_i, m_i,
                                          v_i, bfp, wB);
    dwconv_mfma<<<16 * 384, 256, 0, stream>>>(x, wB, bfp, outp);
}

// Round 12
// 44.320 us; speedup vs baseline: 1.0652x; 1.0652x over previous
//
#include <hip/hip_runtime.h>

#define EPSV 1e-5f

typedef __fp16 f16x8 __attribute__((ext_vector_type(8)));
typedef float f32x4 __attribute__((ext_vector_type(4)));
typedef __fp16 half2v __attribute__((ext_vector_type(2)));

__device__ __forceinline__ unsigned h2_as_u32(half2v h) {
    union { half2v h; unsigned u; } cv;
    cv.h = h;
    return cv.u;
}

#define LROWS 76
#define LSTR32 44            // u32 per row (88 halves, 176B)
#define LBUF (LROWS * LSTR32)  // 3344 u32 = 13376 B per image buffer

// ---------------------------------------------------------------------------
// Kernel 1: fold the 3 branches into one 13x13 kernel + bias; emit per-channel
// MFMA B-fragments: for each dy, 32x16 banded Toeplitz B_dy[k][i] = w[dy][k-i-2]
// in v_mfma_f32_16x16x32_f16 B-fragment order (lane l: i=l&15, k=8*(l>>4)+j).
// ---------------------------------------------------------------------------
__global__ __launch_bounds__(256) void fuse_weights(
    const float* __restrict__ w_large, const float* __restrict__ w_small,
    const float* __restrict__ g_l, const float* __restrict__ b_l,
    const float* __restrict__ m_l, const float* __restrict__ v_l,
    const float* __restrict__ g_s, const float* __restrict__ b_s,
    const float* __restrict__ m_s, const float* __restrict__ v_s,
    const float* __restrict__ g_i, const float* __restrict__ b_i,
    const float* __restrict__ m_i, const float* __restrict__ v_i,
    float* __restrict__ bf, uint4* __restrict__ wB) {
    __shared__ float sw[169];
    const int c = blockIdx.x;
    const int t = threadIdx.x;
    const float sl = g_l[c] * rsqrtf(v_l[c] + EPSV);
    const float ss = g_s[c] * rsqrtf(v_s[c] + EPSV);
    const float si = g_i[c] * rsqrtf(v_i[c] + EPSV);
    if (t < 169) {
        const int ky = t / 13, kx = t % 13;
        float w = w_large[c * 169 + t] * sl;
        if (ky >= 5 && ky <= 7 && kx >= 5 && kx <= 7)
            w += w_small[c * 9 + (ky - 5) * 3 + (kx - 5)] * ss;
        if (t == 6 * 13 + 6) w += si;
        sw[t] = w;
    }
    if (t == 0)
        bf[c] = (b_l[c] - m_l[c] * sl) + (b_s[c] - m_s[c] * ss) +
                (b_i[c] - m_i[c] * si);
    __syncthreads();
    for (int it = t; it < 832; it += 256) {   // 13 dy * 64 lanes
        const int dy = it >> 6;
        const int l = it & 63;
        const int i = l & 15;
        const int kb = (l >> 4) * 8;
        unsigned u[4];
#pragma unroll
        for (int jj = 0; jj < 4; ++jj) {
            const int kx0 = kb + 2 * jj - i - 2;
            const int kx1 = kx0 + 1;
            const float w0 =
                (kx0 >= 0 && kx0 <= 12) ? sw[dy * 13 + kx0] : 0.0f;
            const float w1 =
                (kx1 >= 0 && kx1 <= 12) ? sw[dy * 13 + kx1] : 0.0f;
            u[jj] = h2_as_u32(__builtin_amdgcn_cvt_pkrtz(w0, w1));
        }
        wB[(size_t)c * 832 + it] = make_uint4(u[0], u[1], u[2], u[3]);
    }
}

// ---------------------------------------------------------------------------
// Kernel 2: depthwise 13x13 + bias on matrix cores, 4-image pipelined blocks.
// Block = (c, 4 consecutive n). B-fragments (13 x uint4) + bias loaded ONCE.
// Two LDS f16 image buffers; iteration k: write img k+1 (regs, loaded last
// iter) into buf[1-cur], issue img k+2 global loads (land during compute),
// compute buf[cur] = 13 dy x {4 ds_read_b128 + 4 mfma_f32_16x16x32_f16},
// scalar C-stores, barrier. Staging HBM latency hides under compute.
// ---------------------------------------------------------------------------
__global__ __launch_bounds__(256, 3) void dwconv_mfma(
    const float* __restrict__ x, const uint4* __restrict__ wB,
    const float* __restrict__ bf, float* __restrict__ out) {
    __shared__ __align__(16) unsigned lds[2 * LBUF];

    const int t = threadIdx.x;
    const int bid = blockIdx.x;
    const int c = bid >> 2;
    const int n0 = (bid & 3) << 2;
    const size_t base0 = ((size_t)n0 * 384 + c) * 4096;
    const size_t istep = (size_t)384 * 4096;     // image stride in floats

    // ---- zero halos of BOTH buffers (disjoint from interior writes) ----
#pragma unroll
    for (int b = 0; b < 2; ++b) {
        unsigned* tz = lds + b * LBUF;
        if (t < 120) {   // rows 0..5 and 70..75, u32 0..39
            const int r = t / 10;
            const int rr = (r < 6) ? r : r + 64;
            const int qq = t - r * 10;
            *(uint4*)(tz + rr * LSTR32 + qq * 4) = make_uint4(0u, 0u, 0u, 0u);
        }
        if (t < 128) {   // rows 6..69, u32 {0..3} and {36..39}
            const int r = 6 + (t >> 1);
            const int sb = (t & 1) ? 36 : 0;
            *(uint4*)(tz + r * LSTR32 + sb) = make_uint4(0u, 0u, 0u, 0u);
        }
    }

    // ---- per-block invariants ----
    const int l = t & 63;
    const int wv = t >> 6;                   // wave id -> col tile c0=16*wv
    const float bv = bf[c];

    f16x8 Bf[13];
    {
        const uint4* wbp = wB + (size_t)c * 832 + l;
#pragma unroll
        for (int dy = 0; dy < 13; ++dy) {
            union { uint4 u; f16x8 h; } cv;
            cv.u = wbp[dy * 64];
            Bf[dy] = cv.h;
        }
    }

    // ---- staging geometry: thread -> (row sr, quad sq) ----
    const int sr = t >> 2;                   // 0..63
    const int sq = t & 3;                    // 0..3
    const float* srcb = x + base0 + sr * 64 + sq * 16;
    unsigned* dstA = lds + (sr + 6) * LSTR32 + 4 + sq * 8;           // buf0
    unsigned* dstB = lds + LBUF + (sr + 6) * LSTR32 + 4 + sq * 8;    // buf1

    float4 xr0, xr1, xr2, xr3;

#define ISSUE(k_)                                                      \
    {                                                                  \
        const float4* s_ = (const float4*)(srcb + (size_t)(k_)*istep); \
        xr0 = s_[0]; xr1 = s_[1]; xr2 = s_[2]; xr3 = s_[3];            \
    }

#define WRITEBUF(d_)                                                   \
    {                                                                  \
        unsigned u_[8];                                                \
        u_[0] = h2_as_u32(__builtin_amdgcn_cvt_pkrtz(xr0.x, xr0.y));   \
        u_[1] = h2_as_u32(__builtin_amdgcn_cvt_pkrtz(xr0.z, xr0.w));   \
        u_[2] = h2_as_u32(__builtin_amdgcn_cvt_pkrtz(xr1.x, xr1.y));   \
        u_[3] = h2_as_u32(__builtin_amdgcn_cvt_pkrtz(xr1.z, xr1.w));   \
        u_[4] = h2_as_u32(__builtin_amdgcn_cvt_pkrtz(xr2.x, xr2.y));   \
        u_[5] = h2_as_u32(__builtin_amdgcn_cvt_pkrtz(xr2.z, xr2.w));   \
        u_[6] = h2_as_u32(__builtin_amdgcn_cvt_pkrtz(xr3.x, xr3.y));   \
        u_[7] = h2_as_u32(__builtin_amdgcn_cvt_pkrtz(xr3.z, xr3.w));   \
        *(uint4*)(d_) = make_uint4(u_[0], u_[1], u_[2], u_[3]);        \
        *(uint4*)((d_) + 4) = make_uint4(u_[4], u_[5], u_[6], u_[7]);  \
    }

    // ---- prologue: stage img0 -> buf0, issue img1 ----
    ISSUE(0);
    WRITEBUF(dstA);
    ISSUE(1);
    __syncthreads();

    // ---- compute geometry ----
    const int c0 = wv * 16;
    const int lrow = l & 15;
    const int kb = (l >> 4) * 8;
    const int ocol = c0 + (l & 15);
    const int orow = 4 * (l >> 4);
    const __fp16* ab0 = (const __fp16*)lds + lrow * 88 + c0 + kb;
    const __fp16* ab1 = (const __fp16*)(lds + LBUF) + lrow * 88 + c0 + kb;

#pragma unroll
    for (int k = 0; k < 4; ++k) {
        const int cur = k & 1;
        if (k < 3) {                         // finish staging img k+1
            if (cur == 0) { WRITEBUF(dstB); } else { WRITEBUF(dstA); }
        }
        if (k < 2) ISSUE(k + 2);             // in flight across compute

        const __fp16* ab = cur ? ab1 : ab0;
        f32x4 acc0 = {bv, bv, bv, bv};
        f32x4 acc1 = {bv, bv, bv, bv};
        f32x4 acc2 = {bv, bv, bv, bv};
        f32x4 acc3 = {bv, bv, bv, bv};
#pragma unroll
        for (int dy = 0; dy < 13; ++dy) {
            const f16x8 a0 = *(const f16x8*)(ab + (dy) * 88);
            const f16x8 a1 = *(const f16x8*)(ab + (16 + dy) * 88);
            const f16x8 a2 = *(const f16x8*)(ab + (32 + dy) * 88);
            const f16x8 a3 = *(const f16x8*)(ab + (48 + dy) * 88);
            acc0 = __builtin_amdgcn_mfma_f32_16x16x32_f16(a0, Bf[dy], acc0, 0, 0, 0);
            acc1 = __builtin_amdgcn_mfma_f32_16x16x32_f16(a1, Bf[dy], acc1, 0, 0, 0);
            acc2 = __builtin_amdgcn_mfma_f32_16x16x32_f16(a2, Bf[dy], acc2, 0, 0, 0);
            acc3 = __builtin_amdgcn_mfma_f32_16x16x32_f16(a3, Bf[dy], acc3, 0, 0, 0);
        }

        float* ob = out + base0 + (size_t)k * istep;
#pragma unroll
        for (int q = 0; q < 4; ++q) {
            ob[(orow + q) * 64 + ocol] = acc0[q];
            ob[(16 + orow + q) * 64 + ocol] = acc1[q];
            ob[(32 + orow + q) * 64 + ocol] = acc2[q];
            ob[(48 + orow + q) * 64 + ocol] = acc3[q];
        }
        if (k < 3) __syncthreads();
    }
#undef ISSUE
#undef WRITEBUF
}

// ---------------------------------------------------------------------------
extern "C" void kernel_launch(void* const* d_in, const int* in_sizes, int n_in,
                              void* d_out, int out_size, void* d_ws,
                              size_t ws_size, hipStream_t stream) {
    const float* x = (const float*)d_in[0];
    const float* w_large = (const float*)d_in[1];
    const float* w_small = (const float*)d_in[2];
    const float* g_l = (const float*)d_in[3];
    const float* b_l = (const float*)d_in[4];
    const float* m_l = (const float*)d_in[5];
    const float* v_l = (const float*)d_in[6];
    const float* g_s = (const float*)d_in[7];
    const float* b_s = (const float*)d_in[8];
    const float* m_s = (const float*)d_in[9];
    const float* v_s = (const float*)d_in[10];
    const float* g_i = (const float*)d_in[11];
    const float* b_i = (const float*)d_in[12];
    const float* m_i = (const float*)d_in[13];
    const float* v_i = (const float*)d_in[14];
    float* outp = (float*)d_out;

    // ws layout: bf[384] f32 | wB[384*832] uint4 (5.11 MB)
    float* bfp = (float*)d_ws;
    uint4* wB = (uint4*)(bfp + 384);

    fuse_weights<<<384, 256, 0, stream>>>(w_large, w_small, g_l, b_l, m_l, v_l,
                                          g_s, b_s, m_s, v_s, g_i, b_i, m_i,
                                          v_i, bfp, wB);
    // 1536 blocks: c = bid>>2 (384 channels), 4 images (n) per block
    dwconv_mfma<<<1536, 256, 0, stream>>>(x, wB, bfp, outp);
}

// Round 13
// 41.975 us; speedup vs baseline: 1.1247x; 1.0559x over previous
//
#include <hip/hip_runtime.h>

#define EPSV 1e-5f

typedef __fp16 f16x8 __attribute__((ext_vector_type(8)));
typedef float f32x4 __attribute__((ext_vector_type(4)));
typedef __fp16 half2v __attribute__((ext_vector_type(2)));

__device__ __forceinline__ unsigned h2_as_u32(half2v h) {
    union { half2v h; unsigned u; } cv;
    cv.h = h;
    return cv.u;
}

// LDS layout: 76 rows x 128 halves (256B rows -> rows invisible to banks),
// XOR swizzle: 16B-chunk index ^= (row & 7). Interior at halves [8,72);
// logical chunks 0..9 used; swizzle is bijective within the 16-chunk row.
#define LROWS 76
#define LSTRH 128   // halves per row
#define LSTR32 64   // u32 per row

// ---------------------------------------------------------------------------
// Kernel 1: fold the 3 branches into one 13x13 kernel + bias; emit per-channel
// MFMA B-fragments: for each dy, 32x16 banded Toeplitz B_dy[k][i] = w[dy][k-i-2]
// in v_mfma_f32_16x16x32_f16 B-fragment order (lane l: i=l&15, k=8*(l>>4)+j).
// ---------------------------------------------------------------------------
__global__ __launch_bounds__(256) void fuse_weights(
    const float* __restrict__ w_large, const float* __restrict__ w_small,
    const float* __restrict__ g_l, const float* __restrict__ b_l,
    const float* __restrict__ m_l, const float* __restrict__ v_l,
    const float* __restrict__ g_s, const float* __restrict__ b_s,
    const float* __restrict__ m_s, const float* __restrict__ v_s,
    const float* __restrict__ g_i, const float* __restrict__ b_i,
    const float* __restrict__ m_i, const float* __restrict__ v_i,
    float* __restrict__ bf, uint4* __restrict__ wB) {
    __shared__ float sw[169];
    const int c = blockIdx.x;
    const int t = threadIdx.x;
    const float sl = g_l[c] * rsqrtf(v_l[c] + EPSV);
    const float ss = g_s[c] * rsqrtf(v_s[c] + EPSV);
    const float si = g_i[c] * rsqrtf(v_i[c] + EPSV);
    if (t < 169) {
        const int ky = t / 13, kx = t % 13;
        float w = w_large[c * 169 + t] * sl;
        if (ky >= 5 && ky <= 7 && kx >= 5 && kx <= 7)
            w += w_small[c * 9 + (ky - 5) * 3 + (kx - 5)] * ss;
        if (t == 6 * 13 + 6) w += si;
        sw[t] = w;
    }
    if (t == 0)
        bf[c] = (b_l[c] - m_l[c] * sl) + (b_s[c] - m_s[c] * ss) +
                (b_i[c] - m_i[c] * si);
    __syncthreads();
    for (int it = t; it < 832; it += 256) {   // 13 dy * 64 lanes
        const int dy = it >> 6;
        const int l = it & 63;
        const int i = l & 15;
        const int kb = (l >> 4) * 8;
        unsigned u[4];
#pragma unroll
        for (int jj = 0; jj < 4; ++jj) {
            const int kx0 = kb + 2 * jj - i - 2;
            const int kx1 = kx0 + 1;
            const float w0 =
                (kx0 >= 0 && kx0 <= 12) ? sw[dy * 13 + kx0] : 0.0f;
            const float w1 =
                (kx1 >= 0 && kx1 <= 12) ? sw[dy * 13 + kx1] : 0.0f;
            u[jj] = h2_as_u32(__builtin_amdgcn_cvt_pkrtz(w0, w1));
        }
        wB[(size_t)c * 832 + it] = make_uint4(u[0], u[1], u[2], u[3]);
    }
}

// ---------------------------------------------------------------------------
// Kernel 2: depthwise 13x13 + bias on matrix cores. One block (4 waves) per
// (n,c) image (R10 structure — best measured). Bank-conflict-optimal LDS:
// 256B row stride + chunk^= (row&7) swizzle on BOTH write and read sides ->
// every wave64 b128 access spreads to exactly 8 dwords/bank (HW minimum).
// Wave wv owns 16-col tile c0=16*wv, 4 row-tile accumulators; 13 dy x
// {4 swizzled ds_read_b128 + 4 mfma_f32_16x16x32_f16}; Bf in VGPRs.
// ---------------------------------------------------------------------------
__global__ __launch_bounds__(256, 4) void dwconv_mfma(
    const float* __restrict__ x, const uint4* __restrict__ wB,
    const float* __restrict__ bf, float* __restrict__ out) {
    __shared__ __align__(16) unsigned lds[LROWS * LSTR32];
    __fp16* tile = (__fp16*)lds;

    const int t = threadIdx.x;
    const int img = blockIdx.x;              // n*384 + c
    const int c = __builtin_amdgcn_readfirstlane(img % 384);
    const size_t base = (size_t)img * 4096;

    // ---- issue staging global loads FIRST (latency hides under zeroing) ----
    const int sr = t >> 2;                   // 0..63
    const int sq = t & 3;                    // 0..3
    const float4* srcp = (const float4*)(x + base + sr * 64 + sq * 16);
    const float4 xr0 = srcp[0];
    const float4 xr1 = srcp[1];
    const float4 xr2 = srcp[2];
    const float4 xr3 = srcp[3];

    // ---- zero halos (disjoint from interior writes; no barrier needed) ----
    // top rows 0..5 / bottom rows 70..75: all 16 chunks
    if (t < 192) {
        const int r = t >> 4;
        const int rr = (r < 6) ? r : r + 64;
        *(uint4*)(lds + rr * LSTR32 + (t & 15) * 4) =
            make_uint4(0u, 0u, 0u, 0u);
    }
    // interior rows 6..69: logical chunks 0 (left halo) and 9 (right), swizzled
    if (t < 128) {
        const int r = 6 + (t >> 1);
        const int lc = (t & 1) ? 9 : 0;
        const int pc = lc ^ (r & 7);
        *(uint4*)(lds + r * LSTR32 + pc * 4) = make_uint4(0u, 0u, 0u, 0u);
    }

    // ---- stage interior: row R=sr+6, logical chunks 1+2q / 2+2q, swizzled ----
    {
        const int R = sr + 6;
        unsigned u[8];
        u[0] = h2_as_u32(__builtin_amdgcn_cvt_pkrtz(xr0.x, xr0.y));
        u[1] = h2_as_u32(__builtin_amdgcn_cvt_pkrtz(xr0.z, xr0.w));
        u[2] = h2_as_u32(__builtin_amdgcn_cvt_pkrtz(xr1.x, xr1.y));
        u[3] = h2_as_u32(__builtin_amdgcn_cvt_pkrtz(xr1.z, xr1.w));
        u[4] = h2_as_u32(__builtin_amdgcn_cvt_pkrtz(xr2.x, xr2.y));
        u[5] = h2_as_u32(__builtin_amdgcn_cvt_pkrtz(xr2.z, xr2.w));
        u[6] = h2_as_u32(__builtin_amdgcn_cvt_pkrtz(xr3.x, xr3.y));
        u[7] = h2_as_u32(__builtin_amdgcn_cvt_pkrtz(xr3.z, xr3.w));
        const int p0 = (1 + 2 * sq) ^ (R & 7);
        const int p1 = (2 + 2 * sq) ^ (R & 7);
        *(uint4*)(lds + R * LSTR32 + p0 * 4) = make_uint4(u[0], u[1], u[2], u[3]);
        *(uint4*)(lds + R * LSTR32 + p1 * 4) = make_uint4(u[4], u[5], u[6], u[7]);
    }

    // ---- per-block invariants: B-fragments + bias ----
    const int l = t & 63;
    const int wv = t >> 6;                   // wave id -> col tile c0 = 16*wv
    f16x8 Bf[13];
    {
        const uint4* wbp = wB + (size_t)c * 832 + l;
#pragma unroll
        for (int dy = 0; dy < 13; ++dy) {
            union { uint4 u; f16x8 h; } cv;
            cv.u = wbp[dy * 64];
            Bf[dy] = cv.h;
        }
    }
    const float bv = bf[c];

    __syncthreads();

    const int lrow = l & 15;
    const int cb = 2 * wv + (l >> 4);        // logical 16B-chunk index
    f32x4 acc0 = {bv, bv, bv, bv};
    f32x4 acc1 = {bv, bv, bv, bv};
    f32x4 acc2 = {bv, bv, bv, bv};
    f32x4 acc3 = {bv, bv, bv, bv};

#pragma unroll
    for (int dy = 0; dy < 13; ++dy) {
        const int Ra = lrow + dy;
        const int Rb = Ra + 16;
        const int Rc = Ra + 32;
        const int Rd = Ra + 48;
        const f16x8 a0 =
            *(const f16x8*)(tile + (Ra << 7) + ((cb ^ (Ra & 7)) << 3));
        const f16x8 a1 =
            *(const f16x8*)(tile + (Rb << 7) + ((cb ^ (Rb & 7)) << 3));
        const f16x8 a2 =
            *(const f16x8*)(tile + (Rc << 7) + ((cb ^ (Rc & 7)) << 3));
        const f16x8 a3 =
            *(const f16x8*)(tile + (Rd << 7) + ((cb ^ (Rd & 7)) << 3));
        acc0 = __builtin_amdgcn_mfma_f32_16x16x32_f16(a0, Bf[dy], acc0, 0, 0, 0);
        acc1 = __builtin_amdgcn_mfma_f32_16x16x32_f16(a1, Bf[dy], acc1, 0, 0, 0);
        acc2 = __builtin_amdgcn_mfma_f32_16x16x32_f16(a2, Bf[dy], acc2, 0, 0, 0);
        acc3 = __builtin_amdgcn_mfma_f32_16x16x32_f16(a3, Bf[dy], acc3, 0, 0, 0);
    }

    // C layout: col = 16*wv + (l&15), rows = 16*rt + 4*(l>>4) + q
    const int ocol = 16 * wv + (l & 15);
    const int orow = 4 * (l >> 4);
    float* ob = out + base;
#pragma unroll
    for (int q = 0; q < 4; ++q) {
        ob[(orow + q) * 64 + ocol] = acc0[q];
        ob[(16 + orow + q) * 64 + ocol] = acc1[q];
        ob[(32 + orow + q) * 64 + ocol] = acc2[q];
        ob[(48 + orow + q) * 64 + ocol] = acc3[q];
    }
}

// ---------------------------------------------------------------------------
extern "C" void kernel_launch(void* const* d_in, const int* in_sizes, int n_in,
                              void* d_out, int out_size, void* d_ws,
                              size_t ws_size, hipStream_t stream) {
    const float* x = (const float*)d_in[0];
    const float* w_large = (const float*)d_in[1];
    const float* w_small = (const float*)d_in[2];
    const float* g_l = (const float*)d_in[3];
    const float* b_l = (const float*)d_in[4];
    const float* m_l = (const float*)d_in[5];
    const float* v_l = (const float*)d_in[6];
    const float* g_s = (const float*)d_in[7];
    const float* b_s = (const float*)d_in[8];
    const float* m_s = (const float*)d_in[9];
    const float* v_s = (const float*)d_in[10];
    const float* g_i = (const float*)d_in[11];
    const float* b_i = (const float*)d_in[12];
    const float* m_i = (const float*)d_in[13];
    const float* v_i = (const float*)d_in[14];
    float* outp = (float*)d_out;

    // ws layout: bf[384] f32 | wB[384*832] uint4 (5.11 MB)
    float* bfp = (float*)d_ws;
    uint4* wB = (uint4*)(bfp + 384);

    fuse_weights<<<384, 256, 0, stream>>>(w_large, w_small, g_l, b_l, m_l, v_l,
                                          g_s, b_s, m_s, v_s, g_i, b_i, m_i,
                                          v_i, bfp, wB);
    dwconv_mfma<<<16 * 384, 256, 0, stream>>>(x, wB, bfp, outp);
}